// Round 13
// baseline (205.092 us; speedup 1.0000x reference)
//
#include <hip/hip_runtime.h>
#include <math.h>

// GCN 2-layer, pull-based (CSR by dst via counting sort), no float atomics.
// Algebra: segsum commutes with right-matmul -> both matmuls hoisted:
//   fW1 = feat@W1 (one pass, bf16-packed)
//   h   = relu(segsum(fW1[src]) + b1)
//   p   = h@W2 (compact per-node) ; out = softmax(segsum(p[src]) + b2)
// R12: R11's overlap only covered blocks < ntiles(32-node)=3125 of 6250 hist
//   blocks -- the other half ran bare atomics. 16-node tiles make
//   ntiles == histBlocks (N/16 = E/256 = 6250): EVERY block hides its 256
//   atomics under a tile's FMA/DS work. LDS halves to 4KB (better residency).

#define SCAN_B 1024
#define PAD    16     // counts[node*PAD]: one node per 64B line

__device__ __forceinline__ unsigned f2bf(float x) {
    unsigned u = __float_as_uint(x);
    return (u + 0x7fff + ((u >> 16) & 1)) >> 16;   // RNE, low 16 bits
}

// ---- fused prep: every block: hist(256 edges) + one 16-node fw1 tile ----
__global__ __launch_bounds__(256) void prep_kernel(
    const float4* __restrict__ feat4, const float* __restrict__ W1,
    unsigned* __restrict__ fW1b, const int* __restrict__ dst,
    int* __restrict__ counts, int* __restrict__ rank,
    int n_nodes, int E, int ntiles, int pad)
{
    __shared__ float ft[16][64];          // 4 KB feat tile
    int tid = threadIdx.x, bid = blockIdx.x;

    // hist: issue the atomic FIRST; consume its result at the very end so the
    // round-trip hides under the tile compute below.
    int e = bid * 256 + tid;
    bool he = (e < E);
    int r = 0;
    if (he) r = atomicAdd(&counts[(size_t)dst[e] * pad], 1);

    if (bid < ntiles) {
        int base = bid * 16;
        int lane = tid & 63, w = tid >> 6;
        float4 wc[16];                     // W1 column, vectorized
#pragma unroll
        for (int k4 = 0; k4 < 16; ++k4)
            wc[k4] = make_float4(W1[(k4 * 4 + 0) * 64 + lane],
                                 W1[(k4 * 4 + 1) * 64 + lane],
                                 W1[(k4 * 4 + 2) * 64 + lane],
                                 W1[(k4 * 4 + 3) * 64 + lane]);
        // stage 16 feat rows: exactly one float4 per thread
        {
            int rr = tid >> 4, c = tid & 15;
            int gn = base + rr;
            ((float4*)ft[rr])[c] = (gn < n_nodes) ? feat4[(size_t)gn * 16 + c]
                                                  : make_float4(0.f, 0.f, 0.f, 0.f);
        }
        __syncthreads();
        // wave w: 4 nodes, independent acc chains; 16 b128 broadcasts/node
        for (int i = 0; i < 4; ++i) {
            int rr = w * 4 + i;
            int gn = base + rr;
            if (gn < n_nodes) {
                float acc = 0.f;
                const float4* row4 = (const float4*)ft[rr];
#pragma unroll
                for (int k4 = 0; k4 < 16; ++k4) {
                    float4 f = row4[k4];   // uniform address -> LDS broadcast
                    acc = fmaf(f.x, wc[k4].x,
                          fmaf(f.y, wc[k4].y,
                          fmaf(f.z, wc[k4].z,
                          fmaf(f.w, wc[k4].w, acc))));
                }
                unsigned hb = f2bf(acc);
                unsigned other = __shfl_xor((int)hb, 1, 64);
                if (!(lane & 1))
                    fW1b[(size_t)gn * 32 + (lane >> 1)] = hb | (other << 16);
            }
        }
    }
    if (he && rank) rank[e] = r;          // consume atomic result last
}

// ---------------- scan over N padded counters -> compact offs ----------------
__global__ void scan_phaseA(const int* __restrict__ counts, int* __restrict__ excl,
                            int* __restrict__ blocksums, int n, int pad) {
    __shared__ int lds[SCAN_B];
    int tid = threadIdx.x;
    int i = blockIdx.x * SCAN_B + tid;
    int v = (i < n) ? counts[(size_t)i * pad] : 0;
    lds[tid] = v;
    __syncthreads();
    for (int off = 1; off < SCAN_B; off <<= 1) {
        int t = (tid >= off) ? lds[tid - off] : 0;
        __syncthreads();
        lds[tid] += t;
        __syncthreads();
    }
    if (i < n) excl[i] = lds[tid] - v;
    if (tid == SCAN_B - 1) blocksums[blockIdx.x] = lds[SCAN_B - 1];
}

__global__ void scan_phaseB(int* blocksums, int nb) {
    __shared__ int lds[SCAN_B];
    int tid = threadIdx.x;
    int v = (tid < nb) ? blocksums[tid] : 0;
    lds[tid] = v;
    __syncthreads();
    for (int off = 1; off < SCAN_B; off <<= 1) {
        int t = (tid >= off) ? lds[tid - off] : 0;
        __syncthreads();
        lds[tid] += t;
        __syncthreads();
    }
    if (tid < nb) blocksums[tid] = lds[tid] - v;
}

__global__ void scan_phaseC(int* __restrict__ offs, const int* __restrict__ blocksums,
                            int* __restrict__ cursor, int n, int E) {
    int i = blockIdx.x * blockDim.x + threadIdx.x;
    if (i < n) {
        int o = offs[i] + blocksums[i / SCAN_B];
        offs[i] = o;
        if (cursor) cursor[i] = o;
    } else if (i == n) {
        offs[n] = E;
    }
}

// ---------------- fill: atomic-free via rank, int4 ----------------
__global__ void fill_rank_kernel(const int* __restrict__ src, const int* __restrict__ dst,
                                 const int* __restrict__ rank, const int* __restrict__ offs,
                                 int* __restrict__ ssort, int E) {
    int e0 = ((int)blockIdx.x * 256 + (int)threadIdx.x) * 4;
    if (e0 >= E) return;
    if (e0 + 3 < E) {
        int4 d = ((const int4*)dst)[e0 >> 2];
        int4 sr = ((const int4*)src)[e0 >> 2];
        int4 r = ((const int4*)rank)[e0 >> 2];
        ssort[offs[d.x] + r.x] = sr.x;
        ssort[offs[d.y] + r.y] = sr.y;
        ssort[offs[d.z] + r.z] = sr.z;
        ssort[offs[d.w] + r.w] = sr.w;
    } else {
        for (int e = e0; e < E; ++e)
            ssort[offs[dst[e]] + rank[e]] = src[e];
    }
}

// fallback: cursor atomics (when rank[] doesn't fit)
__global__ void fill_cursor_kernel(const int* __restrict__ src, const int* __restrict__ dst,
                                   int* __restrict__ cursor, int* __restrict__ ssort, int E) {
    int e = (int)blockIdx.x * 256 + threadIdx.x;
    if (e < E) {
        int pos = atomicAdd(&cursor[dst[e]], 1);
        ssort[pos] = src[e];
    }
}

// ------- layer1 tail: b1 + relu + compact dense2 (h@W2 -> p) -------
__device__ __forceinline__ void layer1_tail(float acc, int lane, int node,
                                            const float* __restrict__ b1,
                                            const float* __restrict__ W2,
                                            float* __restrict__ p)
{
    float h = fmaxf(acc + b1[lane], 0.f);
    int j = lane & 15, ks = lane >> 4;
    float pp = 0.f;
#pragma unroll
    for (int i = 0; i < 16; ++i) {
        int kk = ks * 16 + i;
        float hk = __shfl(h, kk, 64);          // broadcast h[kk] from lane kk
        pp = fmaf(hk, W2[kk * 16 + j], pp);
    }
    pp += __shfl_xor(pp, 16, 64);
    pp += __shfl_xor(pp, 32, 64);
    if (ks == 0) p[(size_t)node * 16 + j] = pp;
}

// ---------- layer1: gather bf16 fW1 rows, u32/lane, up to 16 edges in flight ----------
__global__ __launch_bounds__(256) void layer1_kernel(
    const unsigned* __restrict__ fW1b, const int* __restrict__ offs,
    const int* __restrict__ ssort, const float* __restrict__ b1,
    const float* __restrict__ W2, float* __restrict__ p, int n_nodes)
{
    int lane = threadIdx.x & 63;
    int w = threadIdx.x >> 6;
    int node = blockIdx.x * 4 + w;
    if (node >= n_nodes) return;            // no barriers below
    int beg = offs[node], end = offs[node + 1];
    int half = lane >> 5;                   // which edge of the pair
    int sl = lane & 31;                     // col pair -> cols 2sl, 2sl+1
    float ax = 0.f, ay = 0.f;
    int k = beg + half;
    for (; k + 14 < end; k += 16) {         // 16 edges in flight per wave
        int s0 = ssort[k],      s1 = ssort[k + 2],  s2 = ssort[k + 4],  s3 = ssort[k + 6];
        int s4 = ssort[k + 8],  s5 = ssort[k + 10], s6 = ssort[k + 12], s7 = ssort[k + 14];
        unsigned u0 = fW1b[(size_t)s0 * 32 + sl];
        unsigned u1 = fW1b[(size_t)s1 * 32 + sl];
        unsigned u2 = fW1b[(size_t)s2 * 32 + sl];
        unsigned u3 = fW1b[(size_t)s3 * 32 + sl];
        unsigned u4 = fW1b[(size_t)s4 * 32 + sl];
        unsigned u5 = fW1b[(size_t)s5 * 32 + sl];
        unsigned u6 = fW1b[(size_t)s6 * 32 + sl];
        unsigned u7 = fW1b[(size_t)s7 * 32 + sl];
        ax += (__uint_as_float(u0 << 16) + __uint_as_float(u1 << 16))
            + (__uint_as_float(u2 << 16) + __uint_as_float(u3 << 16))
            + (__uint_as_float(u4 << 16) + __uint_as_float(u5 << 16))
            + (__uint_as_float(u6 << 16) + __uint_as_float(u7 << 16));
        ay += (__uint_as_float(u0 & 0xffff0000u) + __uint_as_float(u1 & 0xffff0000u))
            + (__uint_as_float(u2 & 0xffff0000u) + __uint_as_float(u3 & 0xffff0000u))
            + (__uint_as_float(u4 & 0xffff0000u) + __uint_as_float(u5 & 0xffff0000u))
            + (__uint_as_float(u6 & 0xffff0000u) + __uint_as_float(u7 & 0xffff0000u));
    }
    for (; k + 6 < end; k += 8) {
        int s0 = ssort[k], s1 = ssort[k + 2], s2 = ssort[k + 4], s3 = ssort[k + 6];
        unsigned u0 = fW1b[(size_t)s0 * 32 + sl];
        unsigned u1 = fW1b[(size_t)s1 * 32 + sl];
        unsigned u2 = fW1b[(size_t)s2 * 32 + sl];
        unsigned u3 = fW1b[(size_t)s3 * 32 + sl];
        ax += (__uint_as_float(u0 << 16) + __uint_as_float(u1 << 16))
            + (__uint_as_float(u2 << 16) + __uint_as_float(u3 << 16));
        ay += (__uint_as_float(u0 & 0xffff0000u) + __uint_as_float(u1 & 0xffff0000u))
            + (__uint_as_float(u2 & 0xffff0000u) + __uint_as_float(u3 & 0xffff0000u));
    }
    for (; k < end; k += 2) {
        unsigned u = fW1b[(size_t)ssort[k] * 32 + sl];
        ax += __uint_as_float(u << 16);
        ay += __uint_as_float(u & 0xffff0000u);
    }
    ax += __shfl_xor(ax, 32, 64);
    ay += __shfl_xor(ay, 32, 64);
    float am = __shfl(ax, lane >> 1, 64);
    float bm = __shfl(ay, lane >> 1, 64);
    float acc = (lane & 1) ? bm : am;
    layer1_tail(acc, lane, node, b1, W2, p);
}

// ---------- layer2: wave/node, float2 per lane, 16 edges in flight ----------
__global__ __launch_bounds__(256) void layer2_kernel(
    const float2* __restrict__ p2, const int* __restrict__ offs,
    const int* __restrict__ ssort, const float* __restrict__ b2,
    float* __restrict__ out, int n_nodes)
{
    int lane = threadIdx.x & 63;
    int w = threadIdx.x >> 6;
    int node = blockIdx.x * 4 + w;
    if (node >= n_nodes) return;
    int slot = lane >> 3;   // edge slot 0..7
    int cp = lane & 7;      // column pair -> cols 2cp, 2cp+1
    int beg = offs[node], end = offs[node + 1];
    float ax = 0.f, ay = 0.f;
    int k = beg + slot;
    for (; k + 8 < end; k += 16) {      // 16 edges in flight
        int s0 = ssort[k], s1 = ssort[k + 8];
        float2 v0 = p2[(size_t)s0 * 8 + cp];
        float2 v1 = p2[(size_t)s1 * 8 + cp];
        ax += v0.x + v1.x;
        ay += v0.y + v1.y;
    }
    for (; k < end; k += 8) {
        float2 v = p2[(size_t)ssort[k] * 8 + cp];
        ax += v.x;
        ay += v.y;
    }
    ax += __shfl_xor(ax, 8, 64);  ay += __shfl_xor(ay, 8, 64);
    ax += __shfl_xor(ax, 16, 64); ay += __shfl_xor(ay, 16, 64);
    ax += __shfl_xor(ax, 32, 64); ay += __shfl_xor(ay, 32, 64);
    float2 bb = ((const float2*)b2)[cp];
    float vx = ax + bb.x, vy = ay + bb.y;
    float m = fmaxf(vx, vy);
    m = fmaxf(m, __shfl_xor(m, 1, 64));
    m = fmaxf(m, __shfl_xor(m, 2, 64));
    m = fmaxf(m, __shfl_xor(m, 4, 64));
    float ex = __expf(vx - m), ey = __expf(vy - m);
    float s = ex + ey;
    s += __shfl_xor(s, 1, 64);
    s += __shfl_xor(s, 2, 64);
    s += __shfl_xor(s, 4, 64);
    if (slot == 0) {
        float inv = 1.f / s;
        float2 o; o.x = ex * inv; o.y = ey * inv;
        ((float2*)out)[(size_t)node * 8 + cp] = o;
    }
}

extern "C" void kernel_launch(void* const* d_in, const int* in_sizes, int n_in,
                              void* d_out, int out_size, void* d_ws, size_t ws_size,
                              hipStream_t stream) {
    const float* feat = (const float*)d_in[0];
    const float* W1   = (const float*)d_in[1];
    const float* b1   = (const float*)d_in[2];
    const float* W2   = (const float*)d_in[3];
    const float* b2   = (const float*)d_in[4];
    const int*   src  = (const int*)d_in[5];
    const int*   dst  = (const int*)d_in[6];

    int N = in_sizes[0] / 64;
    int E = in_sizes[5];

    // layout (ints): [countsP = max(PAD,16)*N, reused as p after scan] |
    //                fW1b 32N | offs N+1 | bsums SCAN_B | ssort E | rank E
    // = 32.4MB for N=100k,E=1.6M (R10/R11-proven footprint).
    auto need = [&](int pad, bool rnk) -> size_t {
        size_t ints = (size_t)N * (pad > 16 ? pad : 16) + (size_t)N * 32
                    + (size_t)N + 1 + SCAN_B + (size_t)E + (rnk ? (size_t)E : (size_t)N);
        return ints * 4;
    };
    int pad; bool use_rank;
    if (ws_size >= need(PAD, true))   { pad = PAD; use_rank = true; }
    else if (ws_size >= need(1, true)){ pad = 1;   use_rank = true; }
    else                              { pad = 1;   use_rank = false; }

    int*      counts = (int*)d_ws;                       // pad*N; region >= 16N ints
    float*    p      = (float*)d_ws;                     // aliases counts (dead after scan)
    unsigned* fW1b   = (unsigned*)((int*)d_ws + (size_t)N * (pad > 16 ? pad : 16));
    int*      offs   = (int*)(fW1b + (size_t)N * 32);
    int*      bsums  = offs + N + 1;
    int*      ssort  = bsums + SCAN_B;
    int*      rank   = ssort + E;                        // E ints (rank) or N ints (cursor)
    int*      cursor = rank;
    float*    out    = (float*)d_out;

    int nb = (N + SCAN_B - 1) / SCAN_B;
    int histBlocks = (E + 255) / 256;
    int ntiles = (N + 15) / 16;                          // 16-node tiles: == histBlocks here
    int prepGrid = histBlocks > ntiles ? histBlocks : ntiles;

    hipMemsetAsync(counts, 0, (size_t)N * pad * sizeof(int), stream);

    prep_kernel<<<prepGrid, 256, 0, stream>>>(
        (const float4*)feat, W1, fW1b, dst, counts,
        use_rank ? rank : nullptr, N, E, ntiles, pad);

    scan_phaseA<<<nb, SCAN_B, 0, stream>>>(counts, offs, bsums, N, pad);
    scan_phaseB<<<1, SCAN_B, 0, stream>>>(bsums, nb);
    scan_phaseC<<<(N + 1 + 255) / 256, 256, 0, stream>>>(
        offs, bsums, use_rank ? nullptr : cursor, N, E);

    if (use_rank) {
        fill_rank_kernel<<<(E + 1023) / 1024, 256, 0, stream>>>(src, dst, rank, offs, ssort, E);
    } else {
        fill_cursor_kernel<<<(E + 255) / 256, 256, 0, stream>>>(src, dst, cursor, ssort, E);
    }

    layer1_kernel<<<(N + 3) / 4, 256, 0, stream>>>(fW1b, offs, ssort, b1, W2, p, N);
    layer2_kernel<<<(N + 3) / 4, 256, 0, stream>>>((const float2*)p, offs, ssort, b2, out, N);
}

// Round 14
// 201.484 us; speedup vs baseline: 1.0179x; 1.0179x over previous
//
#include <hip/hip_runtime.h>
#include <math.h>

// GCN 2-layer, pull-based (CSR by dst via counting sort), no float atomics.
// Algebra: segsum commutes with right-matmul -> both matmuls hoisted:
//   fW1 = feat@W1 (one pass, bf16-packed)
//   h   = relu(segsum(fW1[src]) + b1)
//   p   = h@W2 (compact per-node) ; out = softmax(segsum(p[src]) + b2)
// R13: vmcnt retires in ISSUE ORDER -> R11/R12's atomic-first layout made
//   every staging-load wait drain the ~800cy atomic too (and the pre-barrier
//   vmcnt(0) drained it again): the overlap never happened. Fix: atomic moved
//   AFTER __syncthreads -- compute phase is pure LDS/VALU (lgkmcnt only), the
//   atomic's sole waiter is the final rank store. Plus layer2 via float4
//   (4 lanes/edge, 32 edges in flight).

#define SCAN_B 1024
#define PAD    16     // counts[node*PAD]: one node per 64B line

__device__ __forceinline__ unsigned f2bf(float x) {
    unsigned u = __float_as_uint(x);
    return (u + 0x7fff + ((u >> 16) & 1)) >> 16;   // RNE, low 16 bits
}

// ---- fused prep: every block: one 16-node fw1 tile + hist(256 edges) ----
__global__ __launch_bounds__(256) void prep_kernel(
    const float4* __restrict__ feat4, const float* __restrict__ W1,
    unsigned* __restrict__ fW1b, const int* __restrict__ dst,
    int* __restrict__ counts, int* __restrict__ rank,
    int n_nodes, int E, int ntiles, int pad)
{
    __shared__ float ft[16][64];          // 4 KB feat tile
    int tid = threadIdx.x, bid = blockIdx.x;
    int lane = tid & 63, w = tid >> 6;

    int e = bid * 256 + tid;
    bool he = (e < E);
    int d = he ? dst[e] : 0;              // plain load, early

    bool tile = (bid < ntiles);
    int base = bid * 16;
    float4 wc[16];
    if (tile) {
        // W1 column, vectorized (issued before the barrier; drained there)
#pragma unroll
        for (int k4 = 0; k4 < 16; ++k4)
            wc[k4] = make_float4(W1[(k4 * 4 + 0) * 64 + lane],
                                 W1[(k4 * 4 + 1) * 64 + lane],
                                 W1[(k4 * 4 + 2) * 64 + lane],
                                 W1[(k4 * 4 + 3) * 64 + lane]);
        // stage 16 feat rows: exactly one float4 per thread
        int rr = tid >> 4, c = tid & 15;
        int gn = base + rr;
        ((float4*)ft[rr])[c] = (gn < n_nodes) ? feat4[(size_t)gn * 16 + c]
                                              : make_float4(0.f, 0.f, 0.f, 0.f);
    }
    __syncthreads();                      // drains ALL staging vmem here

    // atomic issued AFTER the drain: it is now the only outstanding vmem op;
    // compute below is pure LDS/VALU (lgkmcnt), so the round-trip hides fully.
    int r = 0;
    if (he) r = atomicAdd(&counts[(size_t)d * pad], 1);

    if (tile) {
        for (int i = 0; i < 4; ++i) {
            int rr = w * 4 + i;
            int gn = base + rr;
            if (gn < n_nodes) {
                float acc = 0.f;
                const float4* row4 = (const float4*)ft[rr];
#pragma unroll
                for (int k4 = 0; k4 < 16; ++k4) {
                    float4 f = row4[k4];   // uniform address -> LDS broadcast
                    acc = fmaf(f.x, wc[k4].x,
                          fmaf(f.y, wc[k4].y,
                          fmaf(f.z, wc[k4].z,
                          fmaf(f.w, wc[k4].w, acc))));
                }
                unsigned hb = f2bf(acc);
                unsigned other = __shfl_xor((int)hb, 1, 64);
                if (!(lane & 1))
                    fW1b[(size_t)gn * 32 + (lane >> 1)] = hb | (other << 16);
            }
        }
    }
    if (he && rank) rank[e] = r;          // the ONLY consumer of the atomic
}

// ---------------- scan over N padded counters -> compact offs ----------------
__global__ void scan_phaseA(const int* __restrict__ counts, int* __restrict__ excl,
                            int* __restrict__ blocksums, int n, int pad) {
    __shared__ int lds[SCAN_B];
    int tid = threadIdx.x;
    int i = blockIdx.x * SCAN_B + tid;
    int v = (i < n) ? counts[(size_t)i * pad] : 0;
    lds[tid] = v;
    __syncthreads();
    for (int off = 1; off < SCAN_B; off <<= 1) {
        int t = (tid >= off) ? lds[tid - off] : 0;
        __syncthreads();
        lds[tid] += t;
        __syncthreads();
    }
    if (i < n) excl[i] = lds[tid] - v;
    if (tid == SCAN_B - 1) blocksums[blockIdx.x] = lds[SCAN_B - 1];
}

__global__ void scan_phaseB(int* blocksums, int nb) {
    __shared__ int lds[SCAN_B];
    int tid = threadIdx.x;
    int v = (tid < nb) ? blocksums[tid] : 0;
    lds[tid] = v;
    __syncthreads();
    for (int off = 1; off < SCAN_B; off <<= 1) {
        int t = (tid >= off) ? lds[tid - off] : 0;
        __syncthreads();
        lds[tid] += t;
        __syncthreads();
    }
    if (tid < nb) blocksums[tid] = lds[tid] - v;
}

__global__ void scan_phaseC(int* __restrict__ offs, const int* __restrict__ blocksums,
                            int* __restrict__ cursor, int n, int E) {
    int i = blockIdx.x * blockDim.x + threadIdx.x;
    if (i < n) {
        int o = offs[i] + blocksums[i / SCAN_B];
        offs[i] = o;
        if (cursor) cursor[i] = o;
    } else if (i == n) {
        offs[n] = E;
    }
}

// ---------------- fill: atomic-free via rank, int4 ----------------
__global__ void fill_rank_kernel(const int* __restrict__ src, const int* __restrict__ dst,
                                 const int* __restrict__ rank, const int* __restrict__ offs,
                                 int* __restrict__ ssort, int E) {
    int e0 = ((int)blockIdx.x * 256 + (int)threadIdx.x) * 4;
    if (e0 >= E) return;
    if (e0 + 3 < E) {
        int4 d = ((const int4*)dst)[e0 >> 2];
        int4 sr = ((const int4*)src)[e0 >> 2];
        int4 r = ((const int4*)rank)[e0 >> 2];
        ssort[offs[d.x] + r.x] = sr.x;
        ssort[offs[d.y] + r.y] = sr.y;
        ssort[offs[d.z] + r.z] = sr.z;
        ssort[offs[d.w] + r.w] = sr.w;
    } else {
        for (int e = e0; e < E; ++e)
            ssort[offs[dst[e]] + rank[e]] = src[e];
    }
}

// fallback: cursor atomics (when rank[] doesn't fit)
__global__ void fill_cursor_kernel(const int* __restrict__ src, const int* __restrict__ dst,
                                   int* __restrict__ cursor, int* __restrict__ ssort, int E) {
    int e = (int)blockIdx.x * 256 + threadIdx.x;
    if (e < E) {
        int pos = atomicAdd(&cursor[dst[e]], 1);
        ssort[pos] = src[e];
    }
}

// ------- layer1 tail: b1 + relu + compact dense2 (h@W2 -> p) -------
__device__ __forceinline__ void layer1_tail(float acc, int lane, int node,
                                            const float* __restrict__ b1,
                                            const float* __restrict__ W2,
                                            float* __restrict__ p)
{
    float h = fmaxf(acc + b1[lane], 0.f);
    int j = lane & 15, ks = lane >> 4;
    float pp = 0.f;
#pragma unroll
    for (int i = 0; i < 16; ++i) {
        int kk = ks * 16 + i;
        float hk = __shfl(h, kk, 64);          // broadcast h[kk] from lane kk
        pp = fmaf(hk, W2[kk * 16 + j], pp);
    }
    pp += __shfl_xor(pp, 16, 64);
    pp += __shfl_xor(pp, 32, 64);
    if (ks == 0) p[(size_t)node * 16 + j] = pp;
}

// ---------- layer1: gather bf16 fW1 rows, u32/lane, up to 16 edges in flight ----------
__global__ __launch_bounds__(256) void layer1_kernel(
    const unsigned* __restrict__ fW1b, const int* __restrict__ offs,
    const int* __restrict__ ssort, const float* __restrict__ b1,
    const float* __restrict__ W2, float* __restrict__ p, int n_nodes)
{
    int lane = threadIdx.x & 63;
    int w = threadIdx.x >> 6;
    int node = blockIdx.x * 4 + w;
    if (node >= n_nodes) return;            // no barriers below
    int beg = offs[node], end = offs[node + 1];
    int half = lane >> 5;                   // which edge of the pair
    int sl = lane & 31;                     // col pair -> cols 2sl, 2sl+1
    float ax = 0.f, ay = 0.f;
    int k = beg + half;
    for (; k + 14 < end; k += 16) {         // 16 edges in flight per wave
        int s0 = ssort[k],      s1 = ssort[k + 2],  s2 = ssort[k + 4],  s3 = ssort[k + 6];
        int s4 = ssort[k + 8],  s5 = ssort[k + 10], s6 = ssort[k + 12], s7 = ssort[k + 14];
        unsigned u0 = fW1b[(size_t)s0 * 32 + sl];
        unsigned u1 = fW1b[(size_t)s1 * 32 + sl];
        unsigned u2 = fW1b[(size_t)s2 * 32 + sl];
        unsigned u3 = fW1b[(size_t)s3 * 32 + sl];
        unsigned u4 = fW1b[(size_t)s4 * 32 + sl];
        unsigned u5 = fW1b[(size_t)s5 * 32 + sl];
        unsigned u6 = fW1b[(size_t)s6 * 32 + sl];
        unsigned u7 = fW1b[(size_t)s7 * 32 + sl];
        ax += (__uint_as_float(u0 << 16) + __uint_as_float(u1 << 16))
            + (__uint_as_float(u2 << 16) + __uint_as_float(u3 << 16))
            + (__uint_as_float(u4 << 16) + __uint_as_float(u5 << 16))
            + (__uint_as_float(u6 << 16) + __uint_as_float(u7 << 16));
        ay += (__uint_as_float(u0 & 0xffff0000u) + __uint_as_float(u1 & 0xffff0000u))
            + (__uint_as_float(u2 & 0xffff0000u) + __uint_as_float(u3 & 0xffff0000u))
            + (__uint_as_float(u4 & 0xffff0000u) + __uint_as_float(u5 & 0xffff0000u))
            + (__uint_as_float(u6 & 0xffff0000u) + __uint_as_float(u7 & 0xffff0000u));
    }
    for (; k + 6 < end; k += 8) {
        int s0 = ssort[k], s1 = ssort[k + 2], s2 = ssort[k + 4], s3 = ssort[k + 6];
        unsigned u0 = fW1b[(size_t)s0 * 32 + sl];
        unsigned u1 = fW1b[(size_t)s1 * 32 + sl];
        unsigned u2 = fW1b[(size_t)s2 * 32 + sl];
        unsigned u3 = fW1b[(size_t)s3 * 32 + sl];
        ax += (__uint_as_float(u0 << 16) + __uint_as_float(u1 << 16))
            + (__uint_as_float(u2 << 16) + __uint_as_float(u3 << 16));
        ay += (__uint_as_float(u0 & 0xffff0000u) + __uint_as_float(u1 & 0xffff0000u))
            + (__uint_as_float(u2 & 0xffff0000u) + __uint_as_float(u3 & 0xffff0000u));
    }
    for (; k < end; k += 2) {
        unsigned u = fW1b[(size_t)ssort[k] * 32 + sl];
        ax += __uint_as_float(u << 16);
        ay += __uint_as_float(u & 0xffff0000u);
    }
    ax += __shfl_xor(ax, 32, 64);
    ay += __shfl_xor(ay, 32, 64);
    float am = __shfl(ax, lane >> 1, 64);
    float bm = __shfl(ay, lane >> 1, 64);
    float acc = (lane & 1) ? bm : am;
    layer1_tail(acc, lane, node, b1, W2, p);
}

// ---------- layer2: wave/node, float4 per lane, 32 edges in flight ----------
__global__ __launch_bounds__(256) void layer2_kernel(
    const float4* __restrict__ p4, const int* __restrict__ offs,
    const int* __restrict__ ssort, const float* __restrict__ b2,
    float* __restrict__ out, int n_nodes)
{
    int lane = threadIdx.x & 63;
    int w = threadIdx.x >> 6;
    int node = blockIdx.x * 4 + w;
    if (node >= n_nodes) return;
    int slot = lane >> 2;   // edge slot 0..15
    int q = lane & 3;       // col quad -> cols 4q..4q+3
    int beg = offs[node], end = offs[node + 1];
    float a0 = 0.f, a1 = 0.f, a2 = 0.f, a3 = 0.f;
    int k = beg + slot;
    for (; k + 16 < end; k += 32) {     // 32 edges in flight
        int s0 = ssort[k], s1 = ssort[k + 16];
        float4 v0 = p4[(size_t)s0 * 4 + q];
        float4 v1 = p4[(size_t)s1 * 4 + q];
        a0 += v0.x + v1.x;
        a1 += v0.y + v1.y;
        a2 += v0.z + v1.z;
        a3 += v0.w + v1.w;
    }
    for (; k < end; k += 16) {
        float4 v = p4[(size_t)ssort[k] * 4 + q];
        a0 += v.x; a1 += v.y; a2 += v.z; a3 += v.w;
    }
    // reduce over the 16 edge slots (lane bits 2..5)
#pragma unroll
    for (int d = 4; d <= 32; d <<= 1) {
        a0 += __shfl_xor(a0, d, 64);
        a1 += __shfl_xor(a1, d, 64);
        a2 += __shfl_xor(a2, d, 64);
        a3 += __shfl_xor(a3, d, 64);
    }
    float4 bb = ((const float4*)b2)[q];
    float v0 = a0 + bb.x, v1 = a1 + bb.y, v2 = a2 + bb.z, v3 = a3 + bb.w;
    // softmax over 16 classes = 4 q-lanes x 4
    float m = fmaxf(fmaxf(v0, v1), fmaxf(v2, v3));
    m = fmaxf(m, __shfl_xor(m, 1, 64));
    m = fmaxf(m, __shfl_xor(m, 2, 64));
    float e0 = __expf(v0 - m), e1 = __expf(v1 - m);
    float e2 = __expf(v2 - m), e3 = __expf(v3 - m);
    float s = (e0 + e1) + (e2 + e3);
    s += __shfl_xor(s, 1, 64);
    s += __shfl_xor(s, 2, 64);
    if (slot == 0) {
        float inv = 1.f / s;
        float4 o; o.x = e0 * inv; o.y = e1 * inv; o.z = e2 * inv; o.w = e3 * inv;
        ((float4*)out)[(size_t)node * 4 + q] = o;
    }
}

extern "C" void kernel_launch(void* const* d_in, const int* in_sizes, int n_in,
                              void* d_out, int out_size, void* d_ws, size_t ws_size,
                              hipStream_t stream) {
    const float* feat = (const float*)d_in[0];
    const float* W1   = (const float*)d_in[1];
    const float* b1   = (const float*)d_in[2];
    const float* W2   = (const float*)d_in[3];
    const float* b2   = (const float*)d_in[4];
    const int*   src  = (const int*)d_in[5];
    const int*   dst  = (const int*)d_in[6];

    int N = in_sizes[0] / 64;
    int E = in_sizes[5];

    // layout (ints): [countsP = max(PAD,16)*N, reused as p after scan] |
    //                fW1b 32N | offs N+1 | bsums SCAN_B | ssort E | rank E
    auto need = [&](int pad, bool rnk) -> size_t {
        size_t ints = (size_t)N * (pad > 16 ? pad : 16) + (size_t)N * 32
                    + (size_t)N + 1 + SCAN_B + (size_t)E + (rnk ? (size_t)E : (size_t)N);
        return ints * 4;
    };
    int pad; bool use_rank;
    if (ws_size >= need(PAD, true))   { pad = PAD; use_rank = true; }
    else if (ws_size >= need(1, true)){ pad = 1;   use_rank = true; }
    else                              { pad = 1;   use_rank = false; }

    int*      counts = (int*)d_ws;                       // pad*N; region >= 16N ints
    float*    p      = (float*)d_ws;                     // aliases counts (dead after scan)
    unsigned* fW1b   = (unsigned*)((int*)d_ws + (size_t)N * (pad > 16 ? pad : 16));
    int*      offs   = (int*)(fW1b + (size_t)N * 32);
    int*      bsums  = offs + N + 1;
    int*      ssort  = bsums + SCAN_B;
    int*      rank   = ssort + E;                        // E ints (rank) or N ints (cursor)
    int*      cursor = rank;
    float*    out    = (float*)d_out;

    int nb = (N + SCAN_B - 1) / SCAN_B;
    int histBlocks = (E + 255) / 256;
    int ntiles = (N + 15) / 16;                          // == histBlocks here
    int prepGrid = histBlocks > ntiles ? histBlocks : ntiles;

    hipMemsetAsync(counts, 0, (size_t)N * pad * sizeof(int), stream);

    prep_kernel<<<prepGrid, 256, 0, stream>>>(
        (const float4*)feat, W1, fW1b, dst, counts,
        use_rank ? rank : nullptr, N, E, ntiles, pad);

    scan_phaseA<<<nb, SCAN_B, 0, stream>>>(counts, offs, bsums, N, pad);
    scan_phaseB<<<1, SCAN_B, 0, stream>>>(bsums, nb);
    scan_phaseC<<<(N + 1 + 255) / 256, 256, 0, stream>>>(
        offs, bsums, use_rank ? nullptr : cursor, N, E);

    if (use_rank) {
        fill_rank_kernel<<<(E + 1023) / 1024, 256, 0, stream>>>(src, dst, rank, offs, ssort, E);
    } else {
        fill_cursor_kernel<<<(E + 255) / 256, 256, 0, stream>>>(src, dst, cursor, ssort, E);
    }

    layer1_kernel<<<(N + 3) / 4, 256, 0, stream>>>(fW1b, offs, ssort, b1, W2, p, N);
    layer2_kernel<<<(N + 3) / 4, 256, 0, stream>>>((const float4*)p, offs, ssort, b2, out, N);
}